// Round 1
// baseline (1051.195 us; speedup 1.0000x reference)
//
#include <hip/hip_runtime.h>

#define B_ 2
#define T_ 2048
#define C_ 1024
#define H_ 16
#define D_ 64
#define M_ (B_ * T_)       // 4096 rows
#define NQKV_ (3 * C_)     // 3072

// ---------------------------------------------------------------------------
// GEMM: C[M,N] = A[M,K] @ B[K,N] + bias[N]   (fp32, 64x64 tile, 4x4/thread)
// ---------------------------------------------------------------------------
__global__ __launch_bounds__(256) void gemm_bias(
    const float* __restrict__ A, const float* __restrict__ Bm,
    const float* __restrict__ bias, float* __restrict__ Cm,
    int M, int N, int K)
{
    // stride 68: 68 % 32 == 4 -> <=2-way LDS bank aliasing (free); 272B rows keep
    // float4 alignment.
    __shared__ float As[16][68];   // [k][m] (transposed A tile)
    __shared__ float Bs[16][68];   // [k][n]

    const int tid = threadIdx.x;
    const int tx = tid & 15;       // n sub-tile
    const int ty = tid >> 4;       // m sub-tile
    const int n0 = blockIdx.x * 64;
    const int m0 = blockIdx.y * 64;

    float acc[4][4] = {};

    for (int k0 = 0; k0 < K; k0 += 16) {
        // A tile 64(m) x 16(k): one float4 per thread, stored transposed
        {
            const int r = tid >> 2;        // m row 0..63
            const int c = (tid & 3) * 4;   // k col 0,4,8,12
            const float4 a = *(const float4*)(A + (size_t)(m0 + r) * K + (k0 + c));
            As[c + 0][r] = a.x; As[c + 1][r] = a.y;
            As[c + 2][r] = a.z; As[c + 3][r] = a.w;
        }
        // B tile 16(k) x 64(n): one float4 per thread
        {
            const int r = tid >> 4;        // k row 0..15
            const int c = (tid & 15) * 4;  // n col 0..60
            *(float4*)&Bs[r][c] =
                *(const float4*)(Bm + (size_t)(k0 + r) * N + (n0 + c));
        }
        __syncthreads();

        #pragma unroll
        for (int k = 0; k < 16; ++k) {
            const float4 a4 = *(const float4*)&As[k][ty * 4];
            const float4 b4 = *(const float4*)&Bs[k][tx * 4];
            const float av[4] = {a4.x, a4.y, a4.z, a4.w};
            const float bv[4] = {b4.x, b4.y, b4.z, b4.w};
            #pragma unroll
            for (int i = 0; i < 4; ++i)
                #pragma unroll
                for (int j = 0; j < 4; ++j)
                    acc[i][j] = fmaf(av[i], bv[j], acc[i][j]);
        }
        __syncthreads();
    }

    #pragma unroll
    for (int i = 0; i < 4; ++i) {
        const int m = m0 + ty * 4 + i;
        const int n = n0 + tx * 4;
        float4 o;
        o.x = acc[i][0] + bias[n + 0];
        o.y = acc[i][1] + bias[n + 1];
        o.z = acc[i][2] + bias[n + 2];
        o.w = acc[i][3] + bias[n + 3];
        *(float4*)(Cm + (size_t)m * N + n) = o;
    }
}

// ---------------------------------------------------------------------------
// Flash attention (fp32, causal). One block = one (b,h) x 64-query tile.
// qkv layout: [B*T, 3C]; q at +0, k at +C, v at +2C; head h at +h*D.
// Output y: [B*T, C] with y[t, h*D+d].
// ---------------------------------------------------------------------------
__global__ __launch_bounds__(256) void attn(
    const float* __restrict__ qkv, float* __restrict__ y)
{
    __shared__ float Qs[64][68];
    __shared__ float Ks[64][68];   // reused to hold P after S-compute
    __shared__ float Vs[64][68];

    const int tid = threadIdx.x;
    const int tx = tid & 15;       // key / dim sub-tile
    const int ty = tid >> 4;       // query sub-tile
    const int bh = blockIdx.x;     // b*H + h
    const int qt = blockIdx.y;     // query tile index
    const int b = bh >> 4;
    const int h = bh & 15;

    const float* base = qkv + (size_t)b * T_ * NQKV_ + h * D_;

    // ---- load Q tile (pre-scaled by 1/sqrt(D) = 0.125) ----
    #pragma unroll
    for (int rep = 0; rep < 4; ++rep) {
        const int idx = rep * 256 + tid;   // 1024 float4 units
        const int r = idx >> 4;            // row 0..63
        const int c = (idx & 15) * 4;      // d 0..60
        const float4 q = *(const float4*)(base + (size_t)(qt * 64 + r) * NQKV_ + c);
        Qs[r][c + 0] = q.x * 0.125f;
        Qs[r][c + 1] = q.y * 0.125f;
        Qs[r][c + 2] = q.z * 0.125f;
        Qs[r][c + 3] = q.w * 0.125f;
    }

    float o[4][4] = {};
    float m_run[4], l_run[4];
    #pragma unroll
    for (int i = 0; i < 4; ++i) { m_run[i] = -1e30f; l_run[i] = 0.0f; }

    for (int kt = 0; kt <= qt; ++kt) {
        __syncthreads();   // previous tile's P/V reads done before overwrite

        // ---- load K and V tiles ----
        #pragma unroll
        for (int rep = 0; rep < 4; ++rep) {
            const int idx = rep * 256 + tid;
            const int r = idx >> 4;
            const int c = (idx & 15) * 4;
            const float* krow = base + (size_t)(kt * 64 + r) * NQKV_ + C_ + c;
            *(float4*)&Ks[r][c] = *(const float4*)krow;
            *(float4*)&Vs[r][c] = *(const float4*)(krow + C_);
        }
        __syncthreads();

        // ---- S = Q K^T (64x64, 4x4 per thread) ----
        float s[4][4] = {};
        for (int d = 0; d < 64; d += 4) {
            float4 qa[4], kb[4];
            #pragma unroll
            for (int i = 0; i < 4; ++i) qa[i] = *(const float4*)&Qs[ty * 4 + i][d];
            #pragma unroll
            for (int j = 0; j < 4; ++j) kb[j] = *(const float4*)&Ks[tx * 4 + j][d];
            #pragma unroll
            for (int i = 0; i < 4; ++i)
                #pragma unroll
                for (int j = 0; j < 4; ++j)
                    s[i][j] += qa[i].x * kb[j].x + qa[i].y * kb[j].y +
                               qa[i].z * kb[j].z + qa[i].w * kb[j].w;
        }

        // ---- causal mask (only diagonal tile needs it) ----
        if (kt == qt) {
            #pragma unroll
            for (int i = 0; i < 4; ++i)
                #pragma unroll
                for (int j = 0; j < 4; ++j)
                    if (tx * 4 + j > ty * 4 + i) s[i][j] = -1e30f;
        }

        // ---- online softmax update (row reduce across tx via shfl, width 16) ----
        #pragma unroll
        for (int i = 0; i < 4; ++i) {
            float mx = fmaxf(fmaxf(s[i][0], s[i][1]), fmaxf(s[i][2], s[i][3]));
            #pragma unroll
            for (int off = 8; off >= 1; off >>= 1)
                mx = fmaxf(mx, __shfl_xor(mx, off, 16));
            const float m_new = fmaxf(m_run[i], mx);
            const float alpha = __expf(m_run[i] - m_new);
            float sum = 0.0f;
            #pragma unroll
            for (int j = 0; j < 4; ++j) {
                s[i][j] = __expf(s[i][j] - m_new);
                sum += s[i][j];
            }
            #pragma unroll
            for (int off = 8; off >= 1; off >>= 1)
                sum += __shfl_xor(sum, off, 16);
            l_run[i] = l_run[i] * alpha + sum;
            m_run[i] = m_new;
            #pragma unroll
            for (int j = 0; j < 4; ++j) o[i][j] *= alpha;
        }

        __syncthreads();   // everyone done reading Ks -> safe to overwrite with P
        #pragma unroll
        for (int i = 0; i < 4; ++i)
            #pragma unroll
            for (int j = 0; j < 4; ++j)
                Ks[ty * 4 + i][tx * 4 + j] = s[i][j];
        __syncthreads();

        // ---- O += P @ V (P lives in Ks) ----
        for (int k = 0; k < 64; k += 4) {
            float pf[4][4], vf[4][4];
            #pragma unroll
            for (int i = 0; i < 4; ++i) {
                const float4 t = *(const float4*)&Ks[ty * 4 + i][k];
                pf[i][0] = t.x; pf[i][1] = t.y; pf[i][2] = t.z; pf[i][3] = t.w;
            }
            #pragma unroll
            for (int kk = 0; kk < 4; ++kk) {
                const float4 t = *(const float4*)&Vs[k + kk][tx * 4];
                vf[kk][0] = t.x; vf[kk][1] = t.y; vf[kk][2] = t.z; vf[kk][3] = t.w;
            }
            #pragma unroll
            for (int i = 0; i < 4; ++i)
                #pragma unroll
                for (int j = 0; j < 4; ++j)
                    o[i][j] += pf[i][0] * vf[0][j] + pf[i][1] * vf[1][j] +
                               pf[i][2] * vf[2][j] + pf[i][3] * vf[3][j];
        }
    }

    // ---- epilogue: normalize and store ----
    float* outp = y + (size_t)(b * T_ + qt * 64) * C_ + h * D_;
    #pragma unroll
    for (int i = 0; i < 4; ++i) {
        const int q = ty * 4 + i;
        const float inv = 1.0f / l_run[i];
        float4 ov;
        ov.x = o[i][0] * inv; ov.y = o[i][1] * inv;
        ov.z = o[i][2] * inv; ov.w = o[i][3] * inv;
        *(float4*)(outp + (size_t)q * C_ + tx * 4) = ov;
    }
}

// ---------------------------------------------------------------------------
extern "C" void kernel_launch(void* const* d_in, const int* in_sizes, int n_in,
                              void* d_out, int out_size, void* d_ws, size_t ws_size,
                              hipStream_t stream)
{
    const float* x  = (const float*)d_in[0];   // [B,T,C]
    const float* aw = (const float*)d_in[1];   // [C,3C]
    const float* ab = (const float*)d_in[2];   // [3C]
    const float* pw = (const float*)d_in[3];   // [C,C]
    const float* pb = (const float*)d_in[4];   // [C]
    float* out = (float*)d_out;                // [B,T,C]

    float* qkv = (float*)d_ws;                 // [M, 3C] = 50.3 MB
    float* yb  = qkv + (size_t)M_ * NQKV_;     // [M, C]  = 16.8 MB

    // 1) qkv = x @ c_attn_w + c_attn_b
    gemm_bias<<<dim3(NQKV_ / 64, M_ / 64), 256, 0, stream>>>(
        x, aw, ab, qkv, M_, NQKV_, C_);

    // 2) flash attention per (b,h) x 64-query tile
    attn<<<dim3(B_ * H_, T_ / 64), 256, 0, stream>>>(qkv, yb);

    // 3) out = y @ c_proj_w + c_proj_b
    gemm_bias<<<dim3(C_ / 64, M_ / 64), 256, 0, stream>>>(
        yb, pw, pb, out, M_, C_, C_);
}

// Round 2
// 222.766 us; speedup vs baseline: 4.7188x; 4.7188x over previous
//
#include <hip/hip_runtime.h>

#define B_ 2
#define T_ 2048
#define C_ 1024
#define H_ 16
#define D_ 64
#define M_ (B_ * T_)       // 4096 rows
#define NQKV_ (3 * C_)     // 3072

typedef unsigned short us16;
typedef short bf16x8 __attribute__((ext_vector_type(8)));
typedef float f32x4 __attribute__((ext_vector_type(4)));

__device__ __forceinline__ f32x4 mfma16(bf16x8 a, bf16x8 b, f32x4 c) {
    return __builtin_amdgcn_mfma_f32_16x16x32_bf16(a, b, c, 0, 0, 0);
}

// float -> bf16 with round-to-nearest-even
__device__ __forceinline__ us16 f2bf(float f) {
    union { float f; unsigned int u; } v; v.f = f;
    unsigned int r = v.u + 0x7fffu + ((v.u >> 16) & 1u);
    return (us16)(r >> 16);
}

// ---------------------------------------------------------------------------
// fp32 -> bf16 convert (8 elems/thread)
// ---------------------------------------------------------------------------
__global__ __launch_bounds__(256) void cvt_bf16(
    const float* __restrict__ in, us16* __restrict__ out, int n8)
{
    const int i = blockIdx.x * blockDim.x + threadIdx.x;
    if (i >= n8) return;
    const float4 a = ((const float4*)in)[2 * i];
    const float4 b = ((const float4*)in)[2 * i + 1];
    ushort4 lo = { f2bf(a.x), f2bf(a.y), f2bf(a.z), f2bf(a.w) };
    ushort4 hi = { f2bf(b.x), f2bf(b.y), f2bf(b.z), f2bf(b.w) };
    ((ushort4*)out)[2 * i] = lo;
    ((ushort4*)out)[2 * i + 1] = hi;
}

// ---------------------------------------------------------------------------
// W [K][N] fp32  ->  Wt [N][K] bf16   (32x32 LDS tiles)
// ---------------------------------------------------------------------------
__global__ __launch_bounds__(256) void transpose_cvt(
    const float* __restrict__ W, us16* __restrict__ Wt, int K, int N)
{
    __shared__ float tile[32][33];
    const int n0 = blockIdx.x * 32, k0 = blockIdx.y * 32;
    const int t = threadIdx.x;
    {
        const int k = t >> 3, n4 = (t & 7) * 4;
        const float4 v = *(const float4*)(W + (size_t)(k0 + k) * N + n0 + n4);
        tile[k][n4 + 0] = v.x; tile[k][n4 + 1] = v.y;
        tile[k][n4 + 2] = v.z; tile[k][n4 + 3] = v.w;
    }
    __syncthreads();
    {
        const int n = t >> 3, k4 = (t & 7) * 4;
        ushort4 o = { f2bf(tile[k4 + 0][n]), f2bf(tile[k4 + 1][n]),
                      f2bf(tile[k4 + 2][n]), f2bf(tile[k4 + 3][n]) };
        *(ushort4*)(Wt + (size_t)(n0 + n) * K + k0 + k4) = o;
    }
}

// ---------------------------------------------------------------------------
// bf16 MFMA GEMM: C[M][N] = A[M][K] @ Bt[N][K]^T + bias
// 128x128 block tile, BK=64, 4 waves each computing 64x64 (4x4 MFMA tiles).
// out_bf16: write bf16 via LDS-packed coalesced stores, else fp32 scalar.
// ---------------------------------------------------------------------------
__global__ __launch_bounds__(256) void gemm_bf16(
    const us16* __restrict__ A, const us16* __restrict__ Bt,
    const float* __restrict__ bias, void* __restrict__ Cout,
    int M, int N, int K, int out_bf16)
{
    // stride 72 bf16 = 144 B: 16B-aligned rows, 2-way bank aliasing (free)
    __shared__ __align__(16) us16 smem[2 * 128 * 72];
    us16* sA = smem;
    us16* sB = smem + 128 * 72;

    const int tid = threadIdx.x;
    const int lane = tid & 63, wave = tid >> 6;
    const int wr = wave >> 1, wc = wave & 1;
    const int cq = lane & 15, quad = lane >> 4;
    const int m0 = blockIdx.y * 128, n0 = blockIdx.x * 128;

    f32x4 acc[4][4];
    #pragma unroll
    for (int i = 0; i < 4; ++i)
        #pragma unroll
        for (int j = 0; j < 4; ++j)
            acc[i][j] = (f32x4){0.f, 0.f, 0.f, 0.f};

    for (int k0 = 0; k0 < K; k0 += 64) {
        #pragma unroll
        for (int p = 0; p < 4; ++p) {
            const int chunk = p * 256 + tid;
            const int r = chunk >> 3, c8 = (chunk & 7) * 8;
            const uint4 va = *(const uint4*)(A + (size_t)(m0 + r) * K + k0 + c8);
            *(uint4*)(sA + r * 72 + c8) = va;
            const uint4 vb = *(const uint4*)(Bt + (size_t)(n0 + r) * K + k0 + c8);
            *(uint4*)(sB + r * 72 + c8) = vb;
        }
        __syncthreads();

        #pragma unroll
        for (int kk = 0; kk < 64; kk += 32) {
            const int ko = kk + quad * 8;
            bf16x8 af[4], bfg[4];
            #pragma unroll
            for (int i = 0; i < 4; ++i) {
                af[i]  = *(const bf16x8*)(sA + (wr * 64 + i * 16 + cq) * 72 + ko);
                bfg[i] = *(const bf16x8*)(sB + (wc * 64 + i * 16 + cq) * 72 + ko);
            }
            #pragma unroll
            for (int mi = 0; mi < 4; ++mi)
                #pragma unroll
                for (int ni = 0; ni < 4; ++ni)
                    acc[mi][ni] = mfma16(af[mi], bfg[ni], acc[mi][ni]);
        }
        __syncthreads();
    }

    // ---- epilogue ----
    if (out_bf16) {
        us16* Cs = smem;   // 128 x 136 (pad keeps 16B row alignment)
        #pragma unroll
        for (int mi = 0; mi < 4; ++mi)
            #pragma unroll
            for (int ni = 0; ni < 4; ++ni) {
                const int n = n0 + wc * 64 + ni * 16 + cq;
                const float bv = bias[n];
                #pragma unroll
                for (int r = 0; r < 4; ++r)
                    Cs[(wr * 64 + mi * 16 + quad * 4 + r) * 136 +
                       wc * 64 + ni * 16 + cq] = f2bf(acc[mi][ni][r] + bv);
            }
        __syncthreads();
        us16* Co = (us16*)Cout;
        #pragma unroll
        for (int p = 0; p < 8; ++p) {
            const int chunk = p * 256 + tid;
            const int r = chunk >> 4, c = (chunk & 15) * 8;
            *(uint4*)(Co + (size_t)(m0 + r) * N + n0 + c) =
                *(const uint4*)(Cs + r * 136 + c);
        }
    } else {
        float* Co = (float*)Cout;
        #pragma unroll
        for (int mi = 0; mi < 4; ++mi)
            #pragma unroll
            for (int ni = 0; ni < 4; ++ni) {
                const int n = n0 + wc * 64 + ni * 16 + cq;
                const float bv = bias[n];
                #pragma unroll
                for (int r = 0; r < 4; ++r)
                    Co[(size_t)(m0 + wr * 64 + mi * 16 + quad * 4 + r) * N + n] =
                        acc[mi][ni][r] + bv;
            }
    }
}

// ---------------------------------------------------------------------------
// MFMA flash attention (bf16 inputs, fp32 softmax/accum, causal).
// One block = one (b,h) x 64-query tile; 4 waves, wave w owns q rows w*16..+15.
// qkv bf16 [B*T][3C]; y bf16 [B*T][C].
// ---------------------------------------------------------------------------
__global__ __launch_bounds__(256) void attn_mfma(
    const us16* __restrict__ qkv, us16* __restrict__ y)
{
    __shared__ __align__(16) us16 Ks[64][72];   // K tile, [t][d]
    __shared__ __align__(16) us16 Vt[64][72];   // V^T tile, [d][t]
    __shared__ __align__(16) us16 Ps[64][72];   // P, [q][t] (wave-private rows)

    const int tid = threadIdx.x;
    const int lane = tid & 63, wave = tid >> 6;
    const int cq = lane & 15, quad = lane >> 4;
    const int bh = blockIdx.x;
    const int qt = (int)gridDim.y - 1 - (int)blockIdx.y;   // heaviest first
    const int b = bh >> 4, h = bh & 15;

    const us16* base = qkv + (size_t)b * T_ * NQKV_ + h * D_;

    // Q fragments (A operand) straight from global; rows qt*64 + wave*16 + cq
    bf16x8 qf[2];
    {
        const us16* qrow = base + (size_t)(qt * 64 + wave * 16 + cq) * NQKV_;
        qf[0] = *(const bf16x8*)(qrow + quad * 8);
        qf[1] = *(const bf16x8*)(qrow + 32 + quad * 8);
    }

    f32x4 o[4];
    #pragma unroll
    for (int j = 0; j < 4; ++j) o[j] = (f32x4){0.f, 0.f, 0.f, 0.f};
    float m_run[4], l_run[4];
    #pragma unroll
    for (int r = 0; r < 4; ++r) { m_run[r] = -1e30f; l_run[r] = 0.f; }

    const int t2 = tid & 31, dc = tid >> 5;

    for (int kt = 0; kt <= qt; ++kt) {
        __syncthreads();   // previous iteration's MFMA reads complete
        // ---- stage K [t][d] ----
        #pragma unroll
        for (int p = 0; p < 2; ++p) {
            const int chunk = p * 256 + tid;
            const int r = chunk >> 3, c8 = (chunk & 7) * 8;
            const uint4 v = *(const uint4*)(base + (size_t)(kt * 64 + r) * NQKV_ + C_ + c8);
            *(uint4*)(&Ks[r][c8]) = v;
        }
        // ---- stage V transposed: Vt[d][t], packed pair writes ----
        {
            const us16* vp = base + (size_t)(kt * 64 + 2 * t2) * NQKV_ + 2 * C_ + dc * 8;
            const uint4 u0 = *(const uint4*)vp;
            const uint4 u1 = *(const uint4*)(vp + NQKV_);
            const us16* p0 = (const us16*)&u0;
            const us16* p1 = (const us16*)&u1;
            #pragma unroll
            for (int j = 0; j < 8; ++j) {
                const unsigned int packed =
                    (unsigned int)p0[j] | ((unsigned int)p1[j] << 16);
                *(unsigned int*)(&Vt[dc * 8 + j][2 * t2]) = packed;
            }
        }
        __syncthreads();

        // ---- S = Q K^T : 4 col tiles x (K=64 -> 2 mfma) ----
        f32x4 s[4];
        #pragma unroll
        for (int j = 0; j < 4; ++j) {
            const bf16x8 kf0 = *(const bf16x8*)(&Ks[j * 16 + cq][quad * 8]);
            const bf16x8 kf1 = *(const bf16x8*)(&Ks[j * 16 + cq][32 + quad * 8]);
            f32x4 t = (f32x4){0.f, 0.f, 0.f, 0.f};
            t = mfma16(qf[0], kf0, t);
            t = mfma16(qf[1], kf1, t);
            s[j] = t;
        }

        // ---- scale + causal mask (diag tile only) ----
        #pragma unroll
        for (int j = 0; j < 4; ++j)
            #pragma unroll
            for (int r = 0; r < 4; ++r)
                s[j][r] *= 0.125f;
        if (kt == qt) {
            const int qloc = wave * 16 + quad * 4;
            #pragma unroll
            for (int j = 0; j < 4; ++j) {
                const int kloc = j * 16 + cq;
                #pragma unroll
                for (int r = 0; r < 4; ++r)
                    if (kloc > qloc + r) s[j][r] = -1e30f;
            }
        }

        // ---- online softmax (rows = quad*4+r; reduce over 16-lane groups) ----
        #pragma unroll
        for (int r = 0; r < 4; ++r) {
            float mx = fmaxf(fmaxf(s[0][r], s[1][r]), fmaxf(s[2][r], s[3][r]));
            #pragma unroll
            for (int off = 8; off >= 1; off >>= 1)
                mx = fmaxf(mx, __shfl_xor(mx, off));
            const float m_new = fmaxf(m_run[r], mx);
            const float alpha = __expf(m_run[r] - m_new);
            float sum = 0.f;
            #pragma unroll
            for (int j = 0; j < 4; ++j) {
                s[j][r] = __expf(s[j][r] - m_new);
                sum += s[j][r];
            }
            #pragma unroll
            for (int off = 8; off >= 1; off >>= 1)
                sum += __shfl_xor(sum, off);
            l_run[r] = l_run[r] * alpha + sum;
            m_run[r] = m_new;
            #pragma unroll
            for (int j = 0; j < 4; ++j) o[j][r] *= alpha;
        }

        // ---- P -> LDS (wave-private rows; no barrier needed) ----
        #pragma unroll
        for (int j = 0; j < 4; ++j)
            #pragma unroll
            for (int r = 0; r < 4; ++r)
                Ps[wave * 16 + quad * 4 + r][j * 16 + cq] = f2bf(s[j][r]);

        // ---- O += P @ V ----
        const bf16x8 pf0 = *(const bf16x8*)(&Ps[wave * 16 + cq][quad * 8]);
        const bf16x8 pf1 = *(const bf16x8*)(&Ps[wave * 16 + cq][32 + quad * 8]);
        #pragma unroll
        for (int dt = 0; dt < 4; ++dt) {
            const bf16x8 vf0 = *(const bf16x8*)(&Vt[dt * 16 + cq][quad * 8]);
            const bf16x8 vf1 = *(const bf16x8*)(&Vt[dt * 16 + cq][32 + quad * 8]);
            o[dt] = mfma16(pf0, vf0, o[dt]);
            o[dt] = mfma16(pf1, vf1, o[dt]);
        }
    }

    // ---- epilogue: normalize, store bf16 ----
    #pragma unroll
    for (int r = 0; r < 4; ++r) {
        const float inv = 1.0f / l_run[r];
        const int row = qt * 64 + wave * 16 + quad * 4 + r;
        #pragma unroll
        for (int dt = 0; dt < 4; ++dt)
            y[(size_t)(b * T_ + row) * C_ + h * D_ + dt * 16 + cq] =
                f2bf(o[dt][r] * inv);
    }
}

// ---------------------------------------------------------------------------
extern "C" void kernel_launch(void* const* d_in, const int* in_sizes, int n_in,
                              void* d_out, int out_size, void* d_ws, size_t ws_size,
                              hipStream_t stream)
{
    const float* x  = (const float*)d_in[0];   // [B,T,C]
    const float* aw = (const float*)d_in[1];   // [C,3C]
    const float* ab = (const float*)d_in[2];   // [3C]
    const float* pw = (const float*)d_in[3];   // [C,C]
    const float* pb = (const float*)d_in[4];   // [C]
    float* out = (float*)d_out;                // [B,T,C] fp32

    us16* xb   = (us16*)d_ws;                        // [4096][1024]
    us16* awT  = xb  + (size_t)M_ * C_;              // [3072][1024]
    us16* pwT  = awT + (size_t)NQKV_ * C_;           // [1024][1024]
    us16* qkvb = pwT + (size_t)C_ * C_;              // [4096][3072]
    us16* yb   = qkvb + (size_t)M_ * NQKV_;          // [4096][1024]

    // pre-pass: bf16 conversions
    cvt_bf16<<<(M_ * C_ / 8 + 255) / 256, 256, 0, stream>>>(x, xb, M_ * C_ / 8);
    transpose_cvt<<<dim3(NQKV_ / 32, C_ / 32), 256, 0, stream>>>(aw, awT, C_, NQKV_);
    transpose_cvt<<<dim3(C_ / 32, C_ / 32), 256, 0, stream>>>(pw, pwT, C_, C_);

    // 1) qkv = x @ c_attn_w + b   (bf16 out)
    gemm_bf16<<<dim3(NQKV_ / 128, M_ / 128), 256, 0, stream>>>(
        xb, awT, ab, qkvb, M_, NQKV_, C_, 1);

    // 2) flash attention (MFMA)
    attn_mfma<<<dim3(B_ * H_, T_ / 64), 256, 0, stream>>>(qkvb, yb);

    // 3) out = y @ c_proj_w + b   (fp32 out)
    gemm_bf16<<<dim3(C_ / 128, M_ / 128), 256, 0, stream>>>(
        yb, pwT, pb, out, M_, C_, C_, 0);
}